// Round 1
// baseline (409.816 us; speedup 1.0000x reference)
//
#include <hip/hip_runtime.h>
#include <math.h>

#define B_ 64
#define S_ 129
#define F_ 768
#define N3 192            // 3*B
#define BF 49152          // B*F
#define NELEM 6340608     // B*S*F
#define NCHUNK 1548       // S * (F/64)
#define GMAIN 512
#define GSZ 36864         // 192*192

// ws float offsets
#define WS_S1   0
#define WS_S2   49152
#define WS_NM   98304
#define WS_SV   101376
#define WS_C1   104448
#define WS_C0   153600
#define WS_HGM  202752
#define WS_HGS  251904
#define WS_GRAM 301056
#define WS_PART 337920

// out float offsets
#define OUT_LOSS 6340608
#define OUT_NM   6340609
#define OUT_NV   6343681

// ---------------- K1: per-(b,f) sums over S ----------------
__global__ void k_bf_stats(const float* __restrict__ x,
                           float* __restrict__ s1, float* __restrict__ s2) {
    int t = blockIdx.x * 256 + threadIdx.x;      // 0..49151
    int b = t / F_, f = t - b * F_;
    const float* p = x + (size_t)b * S_ * F_ + f;
    float a1 = 0.f, a2 = 0.f;
    for (int s = 0; s < S_; ++s) {
        float v = p[s * F_];
        a1 += v; a2 += v * v;
    }
    s1[t] = a1; s2[t] = a2;
}

// ---------------- K2: per-domain stats -> new_mean/new_var ----------------
__global__ void k_dom(const float* __restrict__ s1bf, const float* __restrict__ s2bf,
                      const int* __restrict__ domain,
                      const float* __restrict__ mean_buf, const float* __restrict__ var_buf,
                      float* __restrict__ nm_tab, float* __restrict__ sv_tab,
                      float* __restrict__ out_nm, float* __restrict__ out_nv) {
    int f = blockIdx.x * 256 + threadIdx.x;
    if (f >= F_) return;
    float a1[4] = {0,0,0,0}, a2[4] = {0,0,0,0};
    int cb[4] = {0,0,0,0};
    for (int b = 0; b < B_; ++b) {
        int d = domain[b];
        float v1 = s1bf[b * F_ + f], v2 = s2bf[b * F_ + f];
#pragma unroll
        for (int k = 0; k < 4; ++k) {
            if (d == k) { a1[k] += v1; a2[k] += v2; cb[k]++; }
        }
    }
#pragma unroll
    for (int d = 0; d < 4; ++d) {
        float nm, nv;
        if (cb[d] > 0) {
            float n = (float)cb[d] * (float)S_;
            float mu = a1[d] / n;
            float var = (a2[d] - n * mu * mu) / fmaxf(n - 1.0f, 1.0f);
            nm = 0.9f * mean_buf[d * F_ + f] + 0.1f * mu;
            nv = 0.9f * var_buf[d * F_ + f] + 0.1f * var;
        } else {
            nm = mean_buf[d * F_ + f];
            nv = var_buf[d * F_ + f];
        }
        out_nm[d * F_ + f] = nm;
        out_nv[d * F_ + f] = nv;
        nm_tab[d * F_ + f] = nm;
        sv_tab[d * F_ + f] = sqrtf(nv + 1e-6f);
    }
}

// ---------------- K2b: per-(b,f) mix/hg coefficients ----------------
__global__ void k_coef(const float* __restrict__ s1bf, const float* __restrict__ s2bf,
                       const float* __restrict__ lmda,
                       const int* __restrict__ domain, const int* __restrict__ d_rand,
                       const float* __restrict__ nm_tab, const float* __restrict__ sv_tab,
                       float* __restrict__ c1, float* __restrict__ c0,
                       float* __restrict__ hgm, float* __restrict__ hgs) {
    int t = blockIdx.x * 256 + threadIdx.x;      // 0..49151
    int b = t / F_, f = t - b * F_;
    float mu = s1bf[t] * (1.0f / (float)S_);
    float v  = (s2bf[t] - (float)S_ * mu * mu) * (1.0f / (float)(S_ - 1));
    float r  = rsqrtf(v + 1e-6f);
    int dm = domain[b];
    int ds = (dm + d_rand[b]) & 3;               // D == 4
    float sv = sv_tab[ds * F_ + f];
    float nm = nm_tab[ds * F_ + f];
    float lam = lmda[b];
    float rs = r * sv;
    c1[t] = lam + (1.0f - lam) * rs;
    c0[t] = (1.0f - lam) * (nm - mu * rs);
    hgm[t] = nm_tab[dm * F_ + f];
    hgs[t] = sv_tab[dm * F_ + f];
}

// ---------------- K3: fused x_mix/hg generation + Gram partials ----------------
template <bool EXCL>
__global__ __launch_bounds__(256, 2)
void k_main(const float* __restrict__ x, const float* __restrict__ hgn,
            const float* __restrict__ c1, const float* __restrict__ c0,
            const float* __restrict__ hgm, const float* __restrict__ hgs,
            float* __restrict__ xmix, float* part, int npart) {
    __shared__ float T[N3 * 65];
    float acc[12][12];
#pragma unroll
    for (int i = 0; i < 12; ++i)
#pragma unroll
        for (int j = 0; j < 12; ++j) acc[i][j] = 0.0f;

    int tid = threadIdx.x;
    int I = (tid >> 4) * 12;
    int J = (tid & 15) * 12;

    for (int q = blockIdx.x; q < NCHUNK; q += gridDim.x) {
        int s = q / 12;
        int f0 = (q - s * 12) * 64;
        // ---- stage 192x64 tile into LDS (rows: x | x_mix | hg) ----
        for (int idx = tid; idx < N3 * 64; idx += 256) {
            int r = idx >> 6, c = idx & 63;
            int b = r & 63, blk = r >> 6;
            int f = f0 + c;
            int g = (b * S_ + s) * F_ + f;
            float v;
            if (blk == 0) {
                v = x[g];
            } else if (blk == 1) {
                v = c1[b * F_ + f] * x[g] + c0[b * F_ + f];
                xmix[g] = v;
            } else {
                v = hgm[b * F_ + f] + hgs[b * F_ + f] * hgn[g];
            }
            T[r * 65 + c] = v;
        }
        __syncthreads();
        // ---- accumulate 12x12 tile of the 192x192 Gram ----
#pragma unroll 2
        for (int c = 0; c < 64; ++c) {
            float a[12], bb[12];
#pragma unroll
            for (int i = 0; i < 12; ++i) a[i] = T[(I + i) * 65 + c];
#pragma unroll
            for (int j = 0; j < 12; ++j) bb[j] = T[(J + j) * 65 + c];
#pragma unroll
            for (int i = 0; i < 12; ++i)
#pragma unroll
                for (int j = 0; j < 12; ++j)
                    acc[i][j] = fmaf(a[i], bb[j], acc[i][j]);
        }
        __syncthreads();
    }

    float* dst = part + (size_t)(blockIdx.x % npart) * GSZ;
#pragma unroll
    for (int i = 0; i < 12; ++i)
#pragma unroll
        for (int j = 0; j < 12; ++j) {
            int o = (I + i) * N3 + (J + j);
            if (EXCL) dst[o] = acc[i][j];
            else atomicAdd(dst + o, acc[i][j]);
        }
}

// ---------------- K3b: reduce partial Grams ----------------
__global__ void k_red(const float* __restrict__ part, float* __restrict__ gram, int npart) {
    int j = blockIdx.x * 256 + threadIdx.x;      // 0..36863
    float s = 0.0f;
    for (int p = 0; p < npart; ++p) s += part[(size_t)p * GSZ + j];
    gram[j] = s;
}

// ---------------- K4: triplet hard loss ----------------
__global__ void k_loss(const float* __restrict__ gram, const int* __restrict__ labels,
                       float* __restrict__ out_loss) {
    __shared__ float sq[N3];
    __shared__ int ln[N3];
    __shared__ float red[N3];
    int i = threadIdx.x;
    sq[i] = gram[i * (N3 + 1)];                  // diagonal
    ln[i] = (i < 128) ? labels[i & 63] : -1;
    __syncthreads();
    int li = ln[i];
    float si = sq[i];
    float ap = -1e30f, an = 1e30f;
    for (int j = 0; j < N3; ++j) {
        float d2 = si + sq[j] - 2.0f * gram[i * N3 + j];
        float dist = sqrtf(fmaxf(d2, 1e-12f));
        if (li == ln[j]) ap = fmaxf(ap, dist);
        else             an = fminf(an, dist);
    }
    float xv = ap - an;
    float sp = fmaxf(xv, 0.0f) + log1pf(expf(-fabsf(xv)));
    red[i] = sp;
    __syncthreads();
    if (i < 64) red[i] = red[i] + red[i + 64] + red[i + 128];
    __syncthreads();
    if (i == 0) {
        float s = 0.0f;
        for (int k = 0; k < 64; ++k) s += red[k];
        out_loss[0] = s * (1.0f / (float)N3);
    }
}

extern "C" void kernel_launch(void* const* d_in, const int* in_sizes, int n_in,
                              void* d_out, int out_size, void* d_ws, size_t ws_size,
                              hipStream_t stream) {
    const float* x        = (const float*)d_in[0];
    const float* lmda     = (const float*)d_in[1];
    const float* mean_buf = (const float*)d_in[2];
    const float* var_buf  = (const float*)d_in[3];
    const float* hgn      = (const float*)d_in[4];
    const int*   labels   = (const int*)d_in[5];
    const int*   domain   = (const int*)d_in[6];
    const int*   d_rand   = (const int*)d_in[7];
    float* out = (float*)d_out;
    float* ws  = (float*)d_ws;

    long avail = (long)(ws_size / 4) - WS_PART;
    int npart = (int)(avail / GSZ);
    if (npart < 1) npart = 1;
    if (npart > GMAIN) npart = GMAIN;
    bool excl = (npart == GMAIN);

    k_bf_stats<<<dim3(192), dim3(256), 0, stream>>>(x, ws + WS_S1, ws + WS_S2);
    k_dom<<<dim3(3), dim3(256), 0, stream>>>(ws + WS_S1, ws + WS_S2, domain,
                                             mean_buf, var_buf,
                                             ws + WS_NM, ws + WS_SV,
                                             out + OUT_NM, out + OUT_NV);
    k_coef<<<dim3(192), dim3(256), 0, stream>>>(ws + WS_S1, ws + WS_S2, lmda,
                                                domain, d_rand,
                                                ws + WS_NM, ws + WS_SV,
                                                ws + WS_C1, ws + WS_C0,
                                                ws + WS_HGM, ws + WS_HGS);
    if (!excl) {
        hipMemsetAsync(ws + WS_PART, 0, (size_t)npart * GSZ * 4, stream);
    }
    if (excl) {
        k_main<true><<<dim3(GMAIN), dim3(256), 0, stream>>>(
            x, hgn, ws + WS_C1, ws + WS_C0, ws + WS_HGM, ws + WS_HGS,
            out, ws + WS_PART, npart);
    } else {
        k_main<false><<<dim3(GMAIN), dim3(256), 0, stream>>>(
            x, hgn, ws + WS_C1, ws + WS_C0, ws + WS_HGM, ws + WS_HGS,
            out, ws + WS_PART, npart);
    }
    k_red<<<dim3(144), dim3(256), 0, stream>>>(ws + WS_PART, ws + WS_GRAM, npart);
    k_loss<<<dim3(1), dim3(N3), 0, stream>>>(ws + WS_GRAM, labels, out + OUT_LOSS);
}

// Round 2
// 268.294 us; speedup vs baseline: 1.5275x; 1.5275x over previous
//
#include <hip/hip_runtime.h>
#include <math.h>

#define B_ 64
#define S_ 129
#define F_ 768
#define N3 192            // 3*B
#define BF 49152          // B*F
#define NCHUNK 1548       // S * (F/64)
#define GMAIN 512
#define GSZ 36864         // 192*192
#define NSPLIT 4

// ws float offsets
#define WS_NM   0
#define WS_SV   3072
#define WS_C1   6144
#define WS_C0   55296
#define WS_HGM  104448
#define WS_HGS  153600
#define WS_S1   202752
#define WS_S2   251904
#define WS_GRAM 301056
#define WS_PART 337920
// S1P/S2P overlay the head of PART (dead before k_main writes PART)
#define WS_S1P  WS_PART
#define WS_S2P  (WS_PART + NSPLIT * BF)

// out float offsets
#define OUT_LOSS 6340608
#define OUT_NM   6340609
#define OUT_NV   6343681

// ---------------- K1: per-(b,f) partial sums over S (split 4 ways) ----------------
__global__ void k_bf_stats(const float* __restrict__ x,
                           float* __restrict__ s1p, float* __restrict__ s2p) {
    int part = blockIdx.x / 192;
    int blk  = blockIdx.x % 192;
    int t = blk * 256 + threadIdx.x;             // 0..49151 -> (b,f)
    int b = t / F_, f = t - b * F_;
    int s0 = part * 33;
    int s1e = (s0 + 33 < S_) ? s0 + 33 : S_;
    const float* p = x + (size_t)b * S_ * F_ + f;
    float a1 = 0.f, a2 = 0.f;
    for (int s = s0; s < s1e; ++s) {
        float v = p[s * F_];
        a1 += v; a2 += v * v;
    }
    s1p[part * BF + t] = a1;
    s2p[part * BF + t] = a2;
}

// ---------------- K1b: combine the 4 partials ----------------
__global__ void k_sum(const float* __restrict__ s1p, const float* __restrict__ s2p,
                      float* __restrict__ s1, float* __restrict__ s2) {
    int t = blockIdx.x * 256 + threadIdx.x;
    float a1 = 0.f, a2 = 0.f;
#pragma unroll
    for (int p = 0; p < NSPLIT; ++p) {
        a1 += s1p[p * BF + t];
        a2 += s2p[p * BF + t];
    }
    s1[t] = a1; s2[t] = a2;
}

// ---------------- K2: per-domain stats -> new_mean/new_var ----------------
__global__ void k_dom(const float* __restrict__ s1bf, const float* __restrict__ s2bf,
                      const int* __restrict__ domain,
                      const float* __restrict__ mean_buf, const float* __restrict__ var_buf,
                      float* __restrict__ nm_tab, float* __restrict__ sv_tab,
                      float* __restrict__ out_nm, float* __restrict__ out_nv) {
    int f = blockIdx.x * 256 + threadIdx.x;
    if (f >= F_) return;
    float a1[4] = {0,0,0,0}, a2[4] = {0,0,0,0};
    int cb[4] = {0,0,0,0};
    for (int b = 0; b < B_; ++b) {
        int d = domain[b];
        float v1 = s1bf[b * F_ + f], v2 = s2bf[b * F_ + f];
#pragma unroll
        for (int k = 0; k < 4; ++k) {
            if (d == k) { a1[k] += v1; a2[k] += v2; cb[k]++; }
        }
    }
#pragma unroll
    for (int d = 0; d < 4; ++d) {
        float nm, nv;
        if (cb[d] > 0) {
            float n = (float)cb[d] * (float)S_;
            float mu = a1[d] / n;
            float var = (a2[d] - n * mu * mu) / fmaxf(n - 1.0f, 1.0f);
            nm = 0.9f * mean_buf[d * F_ + f] + 0.1f * mu;
            nv = 0.9f * var_buf[d * F_ + f] + 0.1f * var;
        } else {
            nm = mean_buf[d * F_ + f];
            nv = var_buf[d * F_ + f];
        }
        out_nm[d * F_ + f] = nm;
        out_nv[d * F_ + f] = nv;
        nm_tab[d * F_ + f] = nm;
        sv_tab[d * F_ + f] = sqrtf(nv + 1e-6f);
    }
}

// ---------------- K2b: per-(b,f) mix/hg coefficients ----------------
__global__ void k_coef(const float* __restrict__ s1bf, const float* __restrict__ s2bf,
                       const float* __restrict__ lmda,
                       const int* __restrict__ domain, const int* __restrict__ d_rand,
                       const float* __restrict__ nm_tab, const float* __restrict__ sv_tab,
                       float* __restrict__ c1, float* __restrict__ c0,
                       float* __restrict__ hgm, float* __restrict__ hgs) {
    int t = blockIdx.x * 256 + threadIdx.x;      // 0..49151
    int b = t / F_, f = t - b * F_;
    float mu = s1bf[t] * (1.0f / (float)S_);
    float v  = (s2bf[t] - (float)S_ * mu * mu) * (1.0f / (float)(S_ - 1));
    float r  = rsqrtf(v + 1e-6f);
    int dm = domain[b];
    int ds = (dm + d_rand[b]) & 3;               // D == 4
    float sv = sv_tab[ds * F_ + f];
    float nm = nm_tab[ds * F_ + f];
    float lam = lmda[b];
    float rs = r * sv;
    c1[t] = lam + (1.0f - lam) * rs;
    c0[t] = (1.0f - lam) * (nm - mu * rs);
    hgm[t] = nm_tab[dm * F_ + f];
    hgs[t] = sv_tab[dm * F_ + f];
}

// ---------------- K3: fused x_mix/hg generation + Gram partials ----------------
// LDS column-major: T[c*196 + r], c in [0,64), r in [0,192). stride 196 floats
// (784 B, 16B-aligned) so float4 reads emit ds_read_b128.
template <bool EXCL>
__global__ __launch_bounds__(256, 2)
void k_main(const float* __restrict__ x, const float* __restrict__ hgn,
            const float* __restrict__ c1, const float* __restrict__ c0,
            const float* __restrict__ hgm, const float* __restrict__ hgs,
            float* __restrict__ xmix, float* part, int npart) {
    __shared__ __align__(16) float T[64 * 196];
    float acc[12][12];
#pragma unroll
    for (int i = 0; i < 12; ++i)
#pragma unroll
        for (int j = 0; j < 12; ++j) acc[i][j] = 0.0f;

    int tid = threadIdx.x;
    int I = (tid >> 4) * 12;
    int J = (tid & 15) * 12;

    for (int q = blockIdx.x; q < NCHUNK; q += gridDim.x) {
        int s = q / 12;
        int f0 = (q - s * 12) * 64;
        // ---- stage: x rows [0,64), x_mix rows [64,128) from one x load ----
#pragma unroll
        for (int k = 0; k < 16; ++k) {
            int idx = tid + k * 256;             // 0..4095
            int b = idx >> 6, c = idx & 63;
            int g = (b * S_ + s) * F_ + f0 + c;
            int bf = b * F_ + f0 + c;
            float xv = x[g];
            float xm = fmaf(c1[bf], xv, c0[bf]);
            xmix[g] = xm;
            T[c * 196 + b] = xv;
            T[c * 196 + 64 + b] = xm;
        }
        // ---- stage: hg rows [128,192) ----
#pragma unroll
        for (int k = 0; k < 16; ++k) {
            int idx = tid + k * 256;
            int b = idx >> 6, c = idx & 63;
            int g = (b * S_ + s) * F_ + f0 + c;
            int bf = b * F_ + f0 + c;
            T[c * 196 + 128 + b] = fmaf(hgs[bf], hgn[g], hgm[bf]);
        }
        __syncthreads();
        // ---- accumulate 12x12 tile of the 192x192 Gram ----
#pragma unroll 2
        for (int c = 0; c < 64; ++c) {
            const float* col = T + c * 196;
            float a[12], bb[12];
            *(float4*)(a)      = *(const float4*)(col + I);
            *(float4*)(a + 4)  = *(const float4*)(col + I + 4);
            *(float4*)(a + 8)  = *(const float4*)(col + I + 8);
            *(float4*)(bb)     = *(const float4*)(col + J);
            *(float4*)(bb + 4) = *(const float4*)(col + J + 4);
            *(float4*)(bb + 8) = *(const float4*)(col + J + 8);
#pragma unroll
            for (int i = 0; i < 12; ++i)
#pragma unroll
                for (int j = 0; j < 12; ++j)
                    acc[i][j] = fmaf(a[i], bb[j], acc[i][j]);
        }
        __syncthreads();
    }

    float* dst = part + (size_t)(blockIdx.x % npart) * GSZ;
#pragma unroll
    for (int i = 0; i < 12; ++i)
#pragma unroll
        for (int j = 0; j < 12; ++j) {
            int o = (I + i) * N3 + (J + j);
            if (EXCL) dst[o] = acc[i][j];
            else atomicAdd(dst + o, acc[i][j]);
        }
}

// ---------------- K3b: reduce partial Grams (grouped, atomic into zeroed gram) ----
__global__ void k_red(const float* __restrict__ part, float* __restrict__ gram, int npart) {
    int g  = blockIdx.x / 144;
    int jb = blockIdx.x % 144;
    int j = jb * 256 + threadIdx.x;              // 0..36863
    int p0 = g * 32;
    int p1 = (p0 + 32 < npart) ? p0 + 32 : npart;
    float s = 0.0f;
    for (int p = p0; p < p1; ++p) s += part[(size_t)p * GSZ + j];
    atomicAdd(gram + j, s);
}

// ---------------- K4: triplet hard loss (one block per row) ----------------
__global__ void k_loss(const float* __restrict__ gram, const int* __restrict__ labels,
                       float* __restrict__ out_loss) {
    __shared__ float sq[N3];
    __shared__ int ln[N3];
    int i = blockIdx.x, lane = threadIdx.x;      // 64 lanes
    for (int k = lane; k < N3; k += 64) {
        sq[k] = gram[k * (N3 + 1)];
        ln[k] = (k < 128) ? labels[k & 63] : -1;
    }
    __syncthreads();
    int li = ln[i];
    float si = sq[i];
    float ap = -1e30f, an = 1e30f;
    for (int j = lane; j < N3; j += 64) {
        float d2 = si + sq[j] - 2.0f * gram[i * N3 + j];
        float dist = sqrtf(fmaxf(d2, 1e-12f));
        bool pos = (li == ln[j]);
        ap = pos ? fmaxf(ap, dist) : ap;
        an = pos ? an : fminf(an, dist);
    }
#pragma unroll
    for (int off = 32; off; off >>= 1) {
        ap = fmaxf(ap, __shfl_xor(ap, off));
        an = fminf(an, __shfl_xor(an, off));
    }
    if (lane == 0) {
        float xv = ap - an;
        float sp = fmaxf(xv, 0.0f) + log1pf(expf(-fabsf(xv)));
        atomicAdd(out_loss, sp * (1.0f / (float)N3));
    }
}

extern "C" void kernel_launch(void* const* d_in, const int* in_sizes, int n_in,
                              void* d_out, int out_size, void* d_ws, size_t ws_size,
                              hipStream_t stream) {
    const float* x        = (const float*)d_in[0];
    const float* lmda     = (const float*)d_in[1];
    const float* mean_buf = (const float*)d_in[2];
    const float* var_buf  = (const float*)d_in[3];
    const float* hgn      = (const float*)d_in[4];
    const int*   labels   = (const int*)d_in[5];
    const int*   domain   = (const int*)d_in[6];
    const int*   d_rand   = (const int*)d_in[7];
    float* out = (float*)d_out;
    float* ws  = (float*)d_ws;

    long avail = (long)(ws_size / 4) - WS_PART;
    int npart = (int)(avail / GSZ);
    if (npart < 1) npart = 1;
    if (npart > GMAIN) npart = GMAIN;
    bool excl = (npart == GMAIN);
    int ngroups = (npart + 31) / 32;

    k_bf_stats<<<dim3(192 * NSPLIT), dim3(256), 0, stream>>>(x, ws + WS_S1P, ws + WS_S2P);
    k_sum<<<dim3(192), dim3(256), 0, stream>>>(ws + WS_S1P, ws + WS_S2P,
                                               ws + WS_S1, ws + WS_S2);
    k_dom<<<dim3(3), dim3(256), 0, stream>>>(ws + WS_S1, ws + WS_S2, domain,
                                             mean_buf, var_buf,
                                             ws + WS_NM, ws + WS_SV,
                                             out + OUT_NM, out + OUT_NV);
    k_coef<<<dim3(192), dim3(256), 0, stream>>>(ws + WS_S1, ws + WS_S2, lmda,
                                                domain, d_rand,
                                                ws + WS_NM, ws + WS_SV,
                                                ws + WS_C1, ws + WS_C0,
                                                ws + WS_HGM, ws + WS_HGS);
    // zero loss + gram accumulators (safe here: after k_sum consumed the S1P/S2P
    // overlay only matters for the PART memset below)
    hipMemsetAsync(out + OUT_LOSS, 0, 4, stream);
    hipMemsetAsync(ws + WS_GRAM, 0, (size_t)GSZ * 4, stream);
    if (!excl) {
        hipMemsetAsync(ws + WS_PART, 0, (size_t)npart * GSZ * 4, stream);
    }
    if (excl) {
        k_main<true><<<dim3(GMAIN), dim3(256), 0, stream>>>(
            x, hgn, ws + WS_C1, ws + WS_C0, ws + WS_HGM, ws + WS_HGS,
            out, ws + WS_PART, npart);
    } else {
        k_main<false><<<dim3(GMAIN), dim3(256), 0, stream>>>(
            x, hgn, ws + WS_C1, ws + WS_C0, ws + WS_HGM, ws + WS_HGS,
            out, ws + WS_PART, npart);
    }
    k_red<<<dim3(ngroups * 144), dim3(256), 0, stream>>>(ws + WS_PART, ws + WS_GRAM, npart);
    k_loss<<<dim3(N3), dim3(64), 0, stream>>>(ws + WS_GRAM, labels, out + OUT_LOSS);
}

// Round 3
// 205.932 us; speedup vs baseline: 1.9901x; 1.3028x over previous
//
#include <hip/hip_runtime.h>
#include <math.h>

#define B_ 64
#define S_ 129
#define F_ 768
#define N3 192            // 3*B
#define BF 49152          // B*F
#define NCHUNK 1548       // S * (F/64)
#define GMAIN 512
#define GSZ 36864         // 192*192
#define NSPLIT 4

// ws float offsets
#define WS_NM   0
#define WS_SV   3072
#define WS_C1   6144
#define WS_C0   55296
#define WS_HGM  104448
#define WS_HGS  153600
#define WS_S1   202752
#define WS_S2   251904
#define WS_GRAM 301056
#define WS_PART 337920
// S1P/S2P overlay the head of PART (dead before k_main writes PART)
#define WS_S1P  WS_PART
#define WS_S2P  (WS_PART + NSPLIT * BF)

// out float offsets
#define OUT_LOSS 6340608
#define OUT_NM   6340609
#define OUT_NV   6343681

typedef unsigned int uint;
using short8v = __attribute__((ext_vector_type(8))) short;
using float4v = __attribute__((ext_vector_type(4))) float;

// ---------------- K1: per-(b,f) partial sums over S (split 4 ways) ----------------
__global__ void k_bf_stats(const float* __restrict__ x,
                           float* __restrict__ s1p, float* __restrict__ s2p) {
    int part = blockIdx.x / 192;
    int blk  = blockIdx.x % 192;
    int t = blk * 256 + threadIdx.x;             // 0..49151 -> (b,f)
    int b = t / F_, f = t - b * F_;
    int s0 = part * 33;
    int s1e = (s0 + 33 < S_) ? s0 + 33 : S_;
    const float* p = x + (size_t)b * S_ * F_ + f;
    float a1 = 0.f, a2 = 0.f;
    for (int s = s0; s < s1e; ++s) {
        float v = p[s * F_];
        a1 += v; a2 += v * v;
    }
    s1p[part * BF + t] = a1;
    s2p[part * BF + t] = a2;
}

// ---------------- K1b: combine the 4 partials ----------------
__global__ void k_sum(const float* __restrict__ s1p, const float* __restrict__ s2p,
                      float* __restrict__ s1, float* __restrict__ s2) {
    int t = blockIdx.x * 256 + threadIdx.x;
    float a1 = 0.f, a2 = 0.f;
#pragma unroll
    for (int p = 0; p < NSPLIT; ++p) {
        a1 += s1p[p * BF + t];
        a2 += s2p[p * BF + t];
    }
    s1[t] = a1; s2[t] = a2;
}

// ---------------- K2: per-domain stats -> new_mean/new_var ----------------
__global__ void k_dom(const float* __restrict__ s1bf, const float* __restrict__ s2bf,
                      const int* __restrict__ domain,
                      const float* __restrict__ mean_buf, const float* __restrict__ var_buf,
                      float* __restrict__ nm_tab, float* __restrict__ sv_tab,
                      float* __restrict__ out_nm, float* __restrict__ out_nv) {
    int f = blockIdx.x * 256 + threadIdx.x;
    if (f >= F_) return;
    float a1[4] = {0,0,0,0}, a2[4] = {0,0,0,0};
    int cb[4] = {0,0,0,0};
    for (int b = 0; b < B_; ++b) {
        int d = domain[b];
        float v1 = s1bf[b * F_ + f], v2 = s2bf[b * F_ + f];
#pragma unroll
        for (int k = 0; k < 4; ++k) {
            if (d == k) { a1[k] += v1; a2[k] += v2; cb[k]++; }
        }
    }
#pragma unroll
    for (int d = 0; d < 4; ++d) {
        float nm, nv;
        if (cb[d] > 0) {
            float n = (float)cb[d] * (float)S_;
            float mu = a1[d] / n;
            float var = (a2[d] - n * mu * mu) / fmaxf(n - 1.0f, 1.0f);
            nm = 0.9f * mean_buf[d * F_ + f] + 0.1f * mu;
            nv = 0.9f * var_buf[d * F_ + f] + 0.1f * var;
        } else {
            nm = mean_buf[d * F_ + f];
            nv = var_buf[d * F_ + f];
        }
        out_nm[d * F_ + f] = nm;
        out_nv[d * F_ + f] = nv;
        nm_tab[d * F_ + f] = nm;
        sv_tab[d * F_ + f] = sqrtf(nv + 1e-6f);
    }
}

// ---------------- K2b: per-(b,f) mix/hg coefficients ----------------
__global__ void k_coef(const float* __restrict__ s1bf, const float* __restrict__ s2bf,
                       const float* __restrict__ lmda,
                       const int* __restrict__ domain, const int* __restrict__ d_rand,
                       const float* __restrict__ nm_tab, const float* __restrict__ sv_tab,
                       float* __restrict__ c1, float* __restrict__ c0,
                       float* __restrict__ hgm, float* __restrict__ hgs) {
    int t = blockIdx.x * 256 + threadIdx.x;      // 0..49151
    int b = t / F_, f = t - b * F_;
    float mu = s1bf[t] * (1.0f / (float)S_);
    float v  = (s2bf[t] - (float)S_ * mu * mu) * (1.0f / (float)(S_ - 1));
    float r  = rsqrtf(v + 1e-6f);
    int dm = domain[b];
    int ds = (dm + d_rand[b]) & 3;               // D == 4
    float sv = sv_tab[ds * F_ + f];
    float nm = nm_tab[ds * F_ + f];
    float lam = lmda[b];
    float rs = r * sv;
    c1[t] = lam + (1.0f - lam) * rs;
    c0[t] = (1.0f - lam) * (nm - mu * rs);
    hgm[t] = nm_tab[dm * F_ + f];
    hgs[t] = sv_tab[dm * F_ + f];
}

// ---------------- bf16 hi/lo split helpers ----------------
// RN float->bf16 on bit patterns; returns packed (b_hi<<16)|a_hi, outputs packed lo.
__device__ __forceinline__ uint packsplit(float a, float b, uint& lopack) {
    uint ua = __float_as_uint(a);
    uint ha = (ua + 0x7FFFu + ((ua >> 16) & 1u)) & 0xFFFF0000u;
    uint ub = __float_as_uint(b);
    uint hb = (ub + 0x7FFFu + ((ub >> 16) & 1u)) & 0xFFFF0000u;
    float la = a - __uint_as_float(ha);
    float lb = b - __uint_as_float(hb);
    uint ula = __float_as_uint(la), ulb = __float_as_uint(lb);
    uint lra = (ula + 0x7FFFu + ((ula >> 16) & 1u)) >> 16;
    uint lrb = (ulb + 0x7FFFu + ((ulb >> 16) & 1u)) & 0xFFFF0000u;
    lopack = lrb | lra;
    return hb | (ha >> 16);
}

// stage one row-segment (16 floats = 2 granules) of one plane into swizzled LDS
__device__ __forceinline__ void split_store(char* lds, int row, int g0, int r7,
                                            float4 v0, float4 v1, float4 v2, float4 v3) {
    uint4 H0, H1, L0, L1;
    H0.x = packsplit(v0.x, v0.y, L0.x);
    H0.y = packsplit(v0.z, v0.w, L0.y);
    H0.z = packsplit(v1.x, v1.y, L0.z);
    H0.w = packsplit(v1.z, v1.w, L0.w);
    H1.x = packsplit(v2.x, v2.y, L1.x);
    H1.y = packsplit(v2.z, v2.w, L1.y);
    H1.z = packsplit(v3.x, v3.y, L1.z);
    H1.w = packsplit(v3.z, v3.w, L1.w);
    int a0 = row * 128 + ((g0 ^ r7) << 4);
    int a1 = row * 128 + (((g0 + 1) ^ r7) << 4);
    *(uint4*)(lds + a0) = H0;
    *(uint4*)(lds + a1) = H1;
    *(uint4*)(lds + 24576 + a0) = L0;
    *(uint4*)(lds + 24576 + a1) = L1;
}

__device__ __forceinline__ float4 fma4(float4 a, float4 x, float4 b) {
    float4 r;
    r.x = fmaf(a.x, x.x, b.x); r.y = fmaf(a.y, x.y, b.y);
    r.z = fmaf(a.z, x.z, b.z); r.w = fmaf(a.w, x.w, b.w);
    return r;
}

// ---------------- K3: fused x_mix/hg generation + MFMA Gram partials ----------------
// LDS: hi plane [192 rows][8 granules of 16B], lo plane at +24576. Granule index
// XOR-swizzled by (row&7) so staging writes and frag reads are conflict-free.
template <bool EXCL>
__global__ __launch_bounds__(256, 2)
void k_main(const float* __restrict__ x, const float* __restrict__ hgn,
            const float* __restrict__ c1, const float* __restrict__ c0,
            const float* __restrict__ hgm, const float* __restrict__ hgs,
            float* __restrict__ xmix, float* part, int npart) {
    __shared__ __align__(16) char LDS[49152];
    float4v acc[6][6];
#pragma unroll
    for (int i = 0; i < 6; ++i)
#pragma unroll
        for (int j = 0; j < 6; ++j)
            acc[i][j] = (float4v){0.f, 0.f, 0.f, 0.f};

    int tid = threadIdx.x;
    int b  = tid >> 2;            // staging row 0..63
    int fq = (tid & 3) << 4;      // f offset within 64-chunk: 0,16,32,48
    int g0 = (tid & 3) << 1;      // first granule
    int r7 = b & 7;
    int w  = tid >> 6;            // wave 0..3
    int wr = (w >> 1) * 96, wc = (w & 1) * 96;
    int lane = tid & 63, m = lane & 15, qd = lane >> 4;

    for (int qq = blockIdx.x; qq < NCHUNK; qq += gridDim.x) {
        int s = qq / 12;
        int f0 = (qq - s * 12) * 64;
        size_t g = ((size_t)b * S_ + s) * F_ + f0 + fq;
        int cb = b * F_ + f0 + fq;

        const float4* xp = (const float4*)(x + g);
        float4 x0 = xp[0], x1 = xp[1], x2 = xp[2], x3 = xp[3];
        const float4* np = (const float4*)(hgn + g);
        float4 n0 = np[0], n1 = np[1], n2 = np[2], n3 = np[3];
        const float4* c1p = (const float4*)(c1 + cb);
        const float4* c0p = (const float4*)(c0 + cb);
        const float4* hmp = (const float4*)(hgm + cb);
        const float4* hsp = (const float4*)(hgs + cb);

        float4 m0 = fma4(c1p[0], x0, c0p[0]);
        float4 m1 = fma4(c1p[1], x1, c0p[1]);
        float4 m2 = fma4(c1p[2], x2, c0p[2]);
        float4 m3 = fma4(c1p[3], x3, c0p[3]);
        float4* xo = (float4*)(xmix + g);
        xo[0] = m0; xo[1] = m1; xo[2] = m2; xo[3] = m3;

        float4 h0 = fma4(hsp[0], n0, hmp[0]);
        float4 h1 = fma4(hsp[1], n1, hmp[1]);
        float4 h2 = fma4(hsp[2], n2, hmp[2]);
        float4 h3 = fma4(hsp[3], n3, hmp[3]);

        split_store(LDS, b,        g0, r7, x0, x1, x2, x3);
        split_store(LDS, 64 + b,   g0, r7, m0, m1, m2, m3);
        split_store(LDS, 128 + b,  g0, r7, h0, h1, h2, h3);
        __syncthreads();

#pragma unroll
        for (int t = 0; t < 2; ++t) {
            short8v Ah[6], Al[6];
#pragma unroll
            for (int i = 0; i < 6; ++i) {
                int row = wr + i * 16 + m;
                int go = (((t << 2) + qd) ^ (row & 7)) << 4;
                const char* p = LDS + row * 128 + go;
                Ah[i] = *(const short8v*)(p);
                Al[i] = *(const short8v*)(p + 24576);
            }
#pragma unroll
            for (int j = 0; j < 6; ++j) {
                int row = wc + j * 16 + m;
                int go = (((t << 2) + qd) ^ (row & 7)) << 4;
                const char* p = LDS + row * 128 + go;
                short8v Bh = *(const short8v*)(p);
                short8v Bl = *(const short8v*)(p + 24576);
#pragma unroll
                for (int i = 0; i < 6; ++i) {
                    acc[i][j] = __builtin_amdgcn_mfma_f32_16x16x32_bf16(Al[i], Bh, acc[i][j], 0, 0, 0);
                    acc[i][j] = __builtin_amdgcn_mfma_f32_16x16x32_bf16(Ah[i], Bl, acc[i][j], 0, 0, 0);
                    acc[i][j] = __builtin_amdgcn_mfma_f32_16x16x32_bf16(Ah[i], Bh, acc[i][j], 0, 0, 0);
                }
            }
        }
        __syncthreads();
    }

    float* dst = part + (size_t)(blockIdx.x % npart) * GSZ;
#pragma unroll
    for (int i = 0; i < 6; ++i)
#pragma unroll
        for (int j = 0; j < 6; ++j) {
            int base = (wr + i * 16 + qd * 4) * N3 + wc + j * 16 + m;
#pragma unroll
            for (int r = 0; r < 4; ++r) {
                int o = base + r * N3;
                if (EXCL) dst[o] = acc[i][j][r];
                else atomicAdd(dst + o, acc[i][j][r]);
            }
        }
}

// ---------------- K3b: reduce partial Grams (grouped, atomic into zeroed gram) ----
__global__ void k_red(const float* __restrict__ part, float* __restrict__ gram, int npart) {
    int g  = blockIdx.x / 144;
    int jb = blockIdx.x % 144;
    int j = jb * 256 + threadIdx.x;              // 0..36863
    int p0 = g * 32;
    int p1 = (p0 + 32 < npart) ? p0 + 32 : npart;
    float s = 0.0f;
    for (int p = p0; p < p1; ++p) s += part[(size_t)p * GSZ + j];
    atomicAdd(gram + j, s);
}

// ---------------- K4: triplet hard loss (one block per row) ----------------
__global__ void k_loss(const float* __restrict__ gram, const int* __restrict__ labels,
                       float* __restrict__ out_loss) {
    __shared__ float sq[N3];
    __shared__ int ln[N3];
    int i = blockIdx.x, lane = threadIdx.x;      // 64 lanes
    for (int k = lane; k < N3; k += 64) {
        sq[k] = gram[k * (N3 + 1)];
        ln[k] = (k < 128) ? labels[k & 63] : -1;
    }
    __syncthreads();
    int li = ln[i];
    float si = sq[i];
    float ap = -1e30f, an = 1e30f;
    for (int j = lane; j < N3; j += 64) {
        float d2 = si + sq[j] - 2.0f * gram[i * N3 + j];
        float dist = sqrtf(fmaxf(d2, 1e-12f));
        bool pos = (li == ln[j]);
        ap = pos ? fmaxf(ap, dist) : ap;
        an = pos ? an : fminf(an, dist);
    }
#pragma unroll
    for (int off = 32; off; off >>= 1) {
        ap = fmaxf(ap, __shfl_xor(ap, off));
        an = fminf(an, __shfl_xor(an, off));
    }
    if (lane == 0) {
        float xv = ap - an;
        float sp = fmaxf(xv, 0.0f) + log1pf(expf(-fabsf(xv)));
        atomicAdd(out_loss, sp * (1.0f / (float)N3));
    }
}

extern "C" void kernel_launch(void* const* d_in, const int* in_sizes, int n_in,
                              void* d_out, int out_size, void* d_ws, size_t ws_size,
                              hipStream_t stream) {
    const float* x        = (const float*)d_in[0];
    const float* lmda     = (const float*)d_in[1];
    const float* mean_buf = (const float*)d_in[2];
    const float* var_buf  = (const float*)d_in[3];
    const float* hgn      = (const float*)d_in[4];
    const int*   labels   = (const int*)d_in[5];
    const int*   domain   = (const int*)d_in[6];
    const int*   d_rand   = (const int*)d_in[7];
    float* out = (float*)d_out;
    float* ws  = (float*)d_ws;

    long avail = (long)(ws_size / 4) - WS_PART;
    int npart = (int)(avail / GSZ);
    if (npart < 1) npart = 1;
    if (npart > GMAIN) npart = GMAIN;
    bool excl = (npart == GMAIN);
    int ngroups = (npart + 31) / 32;

    k_bf_stats<<<dim3(192 * NSPLIT), dim3(256), 0, stream>>>(x, ws + WS_S1P, ws + WS_S2P);
    k_sum<<<dim3(192), dim3(256), 0, stream>>>(ws + WS_S1P, ws + WS_S2P,
                                               ws + WS_S1, ws + WS_S2);
    k_dom<<<dim3(3), dim3(256), 0, stream>>>(ws + WS_S1, ws + WS_S2, domain,
                                             mean_buf, var_buf,
                                             ws + WS_NM, ws + WS_SV,
                                             out + OUT_NM, out + OUT_NV);
    k_coef<<<dim3(192), dim3(256), 0, stream>>>(ws + WS_S1, ws + WS_S2, lmda,
                                                domain, d_rand,
                                                ws + WS_NM, ws + WS_SV,
                                                ws + WS_C1, ws + WS_C0,
                                                ws + WS_HGM, ws + WS_HGS);
    hipMemsetAsync(out + OUT_LOSS, 0, 4, stream);
    hipMemsetAsync(ws + WS_GRAM, 0, (size_t)GSZ * 4, stream);
    if (!excl) {
        hipMemsetAsync(ws + WS_PART, 0, (size_t)npart * GSZ * 4, stream);
    }
    if (excl) {
        k_main<true><<<dim3(GMAIN), dim3(256), 0, stream>>>(
            x, hgn, ws + WS_C1, ws + WS_C0, ws + WS_HGM, ws + WS_HGS,
            out, ws + WS_PART, npart);
    } else {
        k_main<false><<<dim3(GMAIN), dim3(256), 0, stream>>>(
            x, hgn, ws + WS_C1, ws + WS_C0, ws + WS_HGM, ws + WS_HGS,
            out, ws + WS_PART, npart);
    }
    k_red<<<dim3(ngroups * 144), dim3(256), 0, stream>>>(ws + WS_PART, ws + WS_GRAM, npart);
    k_loss<<<dim3(N3), dim3(64), 0, stream>>>(ws + WS_GRAM, labels, out + OUT_LOSS);
}

// Round 4
// 189.938 us; speedup vs baseline: 2.1576x; 1.0842x over previous
//
#include <hip/hip_runtime.h>
#include <math.h>

#define B_ 64
#define S_ 129
#define F_ 768
#define N3 192            // 3*B
#define BF 49152          // B*F
#define NCHUNK 1548       // S * (F/64)
#define GMAIN 256
#define GSZ 36864         // 192*192
#define NSPLIT 4

// ws float offsets
#define WS_NM   0
#define WS_SV   3072
#define WS_C1   6144
#define WS_C0   55296
#define WS_HGM  104448
#define WS_HGS  153600
#define WS_GRAM 301056
#define WS_PART 337920
// S1P/S2P overlay the head of PART (consumed by k_dom/k_coef before k_main writes PART)
#define WS_S1P  WS_PART
#define WS_S2P  (WS_PART + NSPLIT * BF)

// out float offsets
#define OUT_LOSS 6340608
#define OUT_NM   6340609
#define OUT_NV   6343681

typedef unsigned int uint;
using short8v = __attribute__((ext_vector_type(8))) short;
using float4v = __attribute__((ext_vector_type(4))) float;

// ---------------- K1: per-(b,f) partial sums over S (split 4 ways) ----------------
__global__ void k_bf_stats(const float* __restrict__ x,
                           float* __restrict__ s1p, float* __restrict__ s2p) {
    int part = blockIdx.x / 192;
    int blk  = blockIdx.x % 192;
    int t = blk * 256 + threadIdx.x;             // 0..49151 -> (b,f)
    int b = t / F_, f = t - b * F_;
    int s0 = part * 33;
    int s1e = (s0 + 33 < S_) ? s0 + 33 : S_;
    const float* p = x + (size_t)b * S_ * F_ + f;
    float a1 = 0.f, a2 = 0.f;
    for (int s = s0; s < s1e; ++s) {
        float v = p[s * F_];
        a1 += v; a2 += v * v;
    }
    s1p[part * BF + t] = a1;
    s2p[part * BF + t] = a2;
}

// ---------------- K2: per-domain stats -> new_mean/new_var ----------------
__global__ void k_dom(const float* __restrict__ s1p, const float* __restrict__ s2p,
                      const int* __restrict__ domain,
                      const float* __restrict__ mean_buf, const float* __restrict__ var_buf,
                      float* __restrict__ nm_tab, float* __restrict__ sv_tab,
                      float* __restrict__ out_nm, float* __restrict__ out_nv) {
    int f = blockIdx.x * 256 + threadIdx.x;
    if (f >= F_) return;
    float a1[4] = {0,0,0,0}, a2[4] = {0,0,0,0};
    int cb[4] = {0,0,0,0};
    for (int b = 0; b < B_; ++b) {
        int d = domain[b];
        float v1 = 0.f, v2 = 0.f;
#pragma unroll
        for (int p = 0; p < NSPLIT; ++p) {
            v1 += s1p[p * BF + b * F_ + f];
            v2 += s2p[p * BF + b * F_ + f];
        }
#pragma unroll
        for (int k = 0; k < 4; ++k) {
            if (d == k) { a1[k] += v1; a2[k] += v2; cb[k]++; }
        }
    }
#pragma unroll
    for (int d = 0; d < 4; ++d) {
        float nm, nv;
        if (cb[d] > 0) {
            float n = (float)cb[d] * (float)S_;
            float mu = a1[d] / n;
            float var = (a2[d] - n * mu * mu) / fmaxf(n - 1.0f, 1.0f);
            nm = 0.9f * mean_buf[d * F_ + f] + 0.1f * mu;
            nv = 0.9f * var_buf[d * F_ + f] + 0.1f * var;
        } else {
            nm = mean_buf[d * F_ + f];
            nv = var_buf[d * F_ + f];
        }
        out_nm[d * F_ + f] = nm;
        out_nv[d * F_ + f] = nv;
        nm_tab[d * F_ + f] = nm;
        sv_tab[d * F_ + f] = sqrtf(nv + 1e-6f);
    }
}

// ---------------- K2b: per-(b,f) mix/hg coefficients (+ zero gram/loss) ------------
__global__ void k_coef(const float* __restrict__ s1p, const float* __restrict__ s2p,
                       const float* __restrict__ lmda,
                       const int* __restrict__ domain, const int* __restrict__ d_rand,
                       const float* __restrict__ nm_tab, const float* __restrict__ sv_tab,
                       float* __restrict__ c1, float* __restrict__ c0,
                       float* __restrict__ hgm, float* __restrict__ hgs,
                       float* __restrict__ gram, float* __restrict__ out_loss) {
    int t = blockIdx.x * 256 + threadIdx.x;      // 0..49151
    // fold the accumulator zeroing into this kernel (runs before k_main/k_red/k_loss)
    if (blockIdx.x < 144) gram[blockIdx.x * 256 + threadIdx.x] = 0.0f;
    if (blockIdx.x == 144 && threadIdx.x == 0) out_loss[0] = 0.0f;
    int b = t / F_, f = t - b * F_;
    float s1 = 0.f, s2 = 0.f;
#pragma unroll
    for (int p = 0; p < NSPLIT; ++p) {
        s1 += s1p[p * BF + t];
        s2 += s2p[p * BF + t];
    }
    float mu = s1 * (1.0f / (float)S_);
    float v  = (s2 - (float)S_ * mu * mu) * (1.0f / (float)(S_ - 1));
    float r  = rsqrtf(v + 1e-6f);
    int dm = domain[b];
    int ds = (dm + d_rand[b]) & 3;               // D == 4
    float sv = sv_tab[ds * F_ + f];
    float nm = nm_tab[ds * F_ + f];
    float lam = lmda[b];
    float rs = r * sv;
    c1[t] = lam + (1.0f - lam) * rs;
    c0[t] = (1.0f - lam) * (nm - mu * rs);
    hgm[t] = nm_tab[dm * F_ + f];
    hgs[t] = sv_tab[dm * F_ + f];
}

// ---------------- bf16 hi/lo split helpers ----------------
__device__ __forceinline__ uint packsplit(float a, float b, uint& lopack) {
    uint ua = __float_as_uint(a);
    uint ha = (ua + 0x7FFFu + ((ua >> 16) & 1u)) & 0xFFFF0000u;
    uint ub = __float_as_uint(b);
    uint hb = (ub + 0x7FFFu + ((ub >> 16) & 1u)) & 0xFFFF0000u;
    float la = a - __uint_as_float(ha);
    float lb = b - __uint_as_float(hb);
    uint ula = __float_as_uint(la), ulb = __float_as_uint(lb);
    uint lra = (ula + 0x7FFFu + ((ula >> 16) & 1u)) >> 16;
    uint lrb = (ulb + 0x7FFFu + ((ulb >> 16) & 1u)) & 0xFFFF0000u;
    lopack = lrb | lra;
    return hb | (ha >> 16);
}

// stage one granule (8 floats) of one plane-row into swizzled LDS
__device__ __forceinline__ void split_store8(char* lds, int row, int g,
                                             float4 v0, float4 v1) {
    uint4 H, L;
    H.x = packsplit(v0.x, v0.y, L.x);
    H.y = packsplit(v0.z, v0.w, L.y);
    H.z = packsplit(v1.x, v1.y, L.z);
    H.w = packsplit(v1.z, v1.w, L.w);
    int a = row * 128 + ((g ^ (row & 7)) << 4);
    *(uint4*)(lds + a) = H;
    *(uint4*)(lds + 24576 + a) = L;
}

__device__ __forceinline__ float4 fma4(float4 a, float4 x, float4 b) {
    float4 r;
    r.x = fmaf(a.x, x.x, b.x); r.y = fmaf(a.y, x.y, b.y);
    r.z = fmaf(a.z, x.z, b.z); r.w = fmaf(a.w, x.w, b.w);
    return r;
}

// ---------------- K3: fused x_mix/hg generation + MFMA Gram partials ----------------
// 512 threads = 8 waves; wave quadrant 96x48 (6x3 tiles of 16x16) -> 72 AGPR acc.
// Next chunk's x/hgn prefetched into registers before the MFMA section so the
// HBM stream overlaps compute (1 block/CU).
template <bool EXCL>
__global__ __launch_bounds__(512, 2)
void k_main(const float* __restrict__ x, const float* __restrict__ hgn,
            const float* __restrict__ c1, const float* __restrict__ c0,
            const float* __restrict__ hgm, const float* __restrict__ hgs,
            float* __restrict__ xmix, float* part, int npart) {
    __shared__ __align__(16) char LDS[49152];
    float4v acc[6][3];
#pragma unroll
    for (int i = 0; i < 6; ++i)
#pragma unroll
        for (int j = 0; j < 3; ++j)
            acc[i][j] = (float4v){0.f, 0.f, 0.f, 0.f};

    int tid = threadIdx.x;
    int b = tid >> 3;             // staging row 0..63
    int g = tid & 7;              // granule (8 floats)
    int w = tid >> 6;             // wave 0..7
    int wr = (w >> 2) * 96, wc = (w & 3) * 48;
    int lane = tid & 63, m = lane & 15, qd = lane >> 4;

    int q = blockIdx.x;
    size_t goff; int cb;
    {
        int s = q / 12, f0 = (q - s * 12) * 64;
        goff = ((size_t)b * S_ + s) * F_ + f0 + (g << 3);
        cb = b * F_ + f0 + (g << 3);
    }
    float4 X0 = ((const float4*)(x + goff))[0];
    float4 X1 = ((const float4*)(x + goff))[1];
    float4 N0 = ((const float4*)(hgn + goff))[0];
    float4 N1 = ((const float4*)(hgn + goff))[1];

    for (; q < NCHUNK; q += GMAIN) {
        float4 C1a = ((const float4*)(c1 + cb))[0], C1b = ((const float4*)(c1 + cb))[1];
        float4 C0a = ((const float4*)(c0 + cb))[0], C0b = ((const float4*)(c0 + cb))[1];
        float4 HMa = ((const float4*)(hgm + cb))[0], HMb = ((const float4*)(hgm + cb))[1];
        float4 HSa = ((const float4*)(hgs + cb))[0], HSb = ((const float4*)(hgs + cb))[1];

        float4 M0 = fma4(C1a, X0, C0a);
        float4 M1 = fma4(C1b, X1, C0b);
        ((float4*)(xmix + goff))[0] = M0;
        ((float4*)(xmix + goff))[1] = M1;
        float4 H0 = fma4(HSa, N0, HMa);
        float4 H1 = fma4(HSb, N1, HMb);

        split_store8(LDS, b, g, X0, X1);
        split_store8(LDS, 64 + b, g, M0, M1);
        split_store8(LDS, 128 + b, g, H0, H1);
        __syncthreads();

        // prefetch next chunk while MFMA section runs
        int qn = q + GMAIN;
        if (qn < NCHUNK) {
            int s = qn / 12, f0 = (qn - s * 12) * 64;
            goff = ((size_t)b * S_ + s) * F_ + f0 + (g << 3);
            cb = b * F_ + f0 + (g << 3);
            X0 = ((const float4*)(x + goff))[0];
            X1 = ((const float4*)(x + goff))[1];
            N0 = ((const float4*)(hgn + goff))[0];
            N1 = ((const float4*)(hgn + goff))[1];
        }

#pragma unroll
        for (int t = 0; t < 2; ++t) {
            short8v Ah[6], Al[6];
#pragma unroll
            for (int i = 0; i < 6; ++i) {
                int row = wr + i * 16 + m;
                int go = (((t << 2) + qd) ^ (row & 7)) << 4;
                const char* p = LDS + row * 128 + go;
                Ah[i] = *(const short8v*)(p);
                Al[i] = *(const short8v*)(p + 24576);
            }
#pragma unroll
            for (int j = 0; j < 3; ++j) {
                int row = wc + j * 16 + m;
                int go = (((t << 2) + qd) ^ (row & 7)) << 4;
                const char* p = LDS + row * 128 + go;
                short8v Bh = *(const short8v*)(p);
                short8v Bl = *(const short8v*)(p + 24576);
#pragma unroll
                for (int i = 0; i < 6; ++i) {
                    acc[i][j] = __builtin_amdgcn_mfma_f32_16x16x32_bf16(Al[i], Bh, acc[i][j], 0, 0, 0);
                    acc[i][j] = __builtin_amdgcn_mfma_f32_16x16x32_bf16(Ah[i], Bl, acc[i][j], 0, 0, 0);
                    acc[i][j] = __builtin_amdgcn_mfma_f32_16x16x32_bf16(Ah[i], Bh, acc[i][j], 0, 0, 0);
                }
            }
        }
        __syncthreads();
    }

    float* dst = part + (size_t)(blockIdx.x % npart) * GSZ;
#pragma unroll
    for (int i = 0; i < 6; ++i)
#pragma unroll
        for (int j = 0; j < 3; ++j) {
            int base = (wr + i * 16 + qd * 4) * N3 + wc + j * 16 + m;
#pragma unroll
            for (int r = 0; r < 4; ++r) {
                int o = base + r * N3;
                if (EXCL) dst[o] = acc[i][j][r];
                else atomicAdd(dst + o, acc[i][j][r]);
            }
        }
}

// ---------------- K3b: reduce partial Grams (grouped, atomic into zeroed gram) ----
__global__ void k_red(const float* __restrict__ part, float* __restrict__ gram, int npart) {
    int g  = blockIdx.x / 144;
    int jb = blockIdx.x % 144;
    int j = jb * 256 + threadIdx.x;              // 0..36863
    int p0 = g * 32;
    int p1 = (p0 + 32 < npart) ? p0 + 32 : npart;
    float s = 0.0f;
    for (int p = p0; p < p1; ++p) s += part[(size_t)p * GSZ + j];
    atomicAdd(gram + j, s);
}

// ---------------- K4: triplet hard loss (one block per row) ----------------
__global__ void k_loss(const float* __restrict__ gram, const int* __restrict__ labels,
                       float* __restrict__ out_loss) {
    __shared__ float sq[N3];
    __shared__ int ln[N3];
    int i = blockIdx.x, lane = threadIdx.x;      // 64 lanes
    for (int k = lane; k < N3; k += 64) {
        sq[k] = gram[k * (N3 + 1)];
        ln[k] = (k < 128) ? labels[k & 63] : -1;
    }
    __syncthreads();
    int li = ln[i];
    float si = sq[i];
    float ap = -1e30f, an = 1e30f;
    for (int j = lane; j < N3; j += 64) {
        float d2 = si + sq[j] - 2.0f * gram[i * N3 + j];
        float dist = sqrtf(fmaxf(d2, 1e-12f));
        bool pos = (li == ln[j]);
        ap = pos ? fmaxf(ap, dist) : ap;
        an = pos ? an : fminf(an, dist);
    }
#pragma unroll
    for (int off = 32; off; off >>= 1) {
        ap = fmaxf(ap, __shfl_xor(ap, off));
        an = fminf(an, __shfl_xor(an, off));
    }
    if (lane == 0) {
        float xv = ap - an;
        float sp = fmaxf(xv, 0.0f) + log1pf(expf(-fabsf(xv)));
        atomicAdd(out_loss, sp * (1.0f / (float)N3));
    }
}

extern "C" void kernel_launch(void* const* d_in, const int* in_sizes, int n_in,
                              void* d_out, int out_size, void* d_ws, size_t ws_size,
                              hipStream_t stream) {
    const float* x        = (const float*)d_in[0];
    const float* lmda     = (const float*)d_in[1];
    const float* mean_buf = (const float*)d_in[2];
    const float* var_buf  = (const float*)d_in[3];
    const float* hgn      = (const float*)d_in[4];
    const int*   labels   = (const int*)d_in[5];
    const int*   domain   = (const int*)d_in[6];
    const int*   d_rand   = (const int*)d_in[7];
    float* out = (float*)d_out;
    float* ws  = (float*)d_ws;

    long avail = (long)(ws_size / 4) - WS_PART;
    int npart = (int)(avail / GSZ);
    if (npart < 1) npart = 1;
    if (npart > GMAIN) npart = GMAIN;
    bool excl = (npart == GMAIN);
    int ngroups = (npart + 31) / 32;

    k_bf_stats<<<dim3(192 * NSPLIT), dim3(256), 0, stream>>>(x, ws + WS_S1P, ws + WS_S2P);
    k_dom<<<dim3(3), dim3(256), 0, stream>>>(ws + WS_S1P, ws + WS_S2P, domain,
                                             mean_buf, var_buf,
                                             ws + WS_NM, ws + WS_SV,
                                             out + OUT_NM, out + OUT_NV);
    k_coef<<<dim3(192), dim3(256), 0, stream>>>(ws + WS_S1P, ws + WS_S2P, lmda,
                                                domain, d_rand,
                                                ws + WS_NM, ws + WS_SV,
                                                ws + WS_C1, ws + WS_C0,
                                                ws + WS_HGM, ws + WS_HGS,
                                                ws + WS_GRAM, out + OUT_LOSS);
    if (!excl) {
        hipMemsetAsync(ws + WS_PART, 0, (size_t)npart * GSZ * 4, stream);
    }
    if (excl) {
        k_main<true><<<dim3(GMAIN), dim3(512), 0, stream>>>(
            x, hgn, ws + WS_C1, ws + WS_C0, ws + WS_HGM, ws + WS_HGS,
            out, ws + WS_PART, npart);
    } else {
        k_main<false><<<dim3(GMAIN), dim3(512), 0, stream>>>(
            x, hgn, ws + WS_C1, ws + WS_C0, ws + WS_HGM, ws + WS_HGS,
            out, ws + WS_PART, npart);
    }
    k_red<<<dim3(ngroups * 144), dim3(256), 0, stream>>>(ws + WS_PART, ws + WS_GRAM, npart);
    k_loss<<<dim3(N3), dim3(64), 0, stream>>>(ws + WS_GRAM, labels, out + OUT_LOSS);
}